// Round 5
// baseline (529.138 us; speedup 1.0000x reference)
//
#include <hip/hip_runtime.h>

// MultiHeadattention: B=2, S=2048, D=1024, H=16, Dk=64.
// QUIRK: softmax over the HEAD axis (dim=1): attn[b,h,q,k] = exp(s)/sum_h' exp(s').
// R5: per-head layouts Qh/Kh/OPh[(b,h,q)][dk] -> dense VMEM (R4 was 16-line scatter
// per load, TA-bound: MfmaUtil 8.5 / VALU 21 / HBM 9 all idle); attn2 software-
// pipelined (kf/rv double-buffered); proj GEMMs use bf16 W via global_load_lds on
// both operands; Vt epilogue transposed through LDS (dense stores); psum folded
// into out-proj A-staging.

#define D_MODEL 1024
#define NH 16
#define DKH 64
#define SEQ 2048
#define NB 2
#define NTOK (NB * SEQ)
#define SCALE 0.125f

typedef float f32x4 __attribute__((ext_vector_type(4)));
typedef short bf16x8 __attribute__((ext_vector_type(8)));

static __device__ __forceinline__ unsigned short f2bf(float x) {
    union { float f; unsigned int u; } c; c.f = x;
    unsigned int r = (c.u + 0x7FFFu + ((c.u >> 16) & 1u)) >> 16;
    return (unsigned short)r;
}
static __device__ __forceinline__ unsigned int pack2(float a, float b) {
    return (unsigned int)f2bf(a) | ((unsigned int)f2bf(b) << 16);
}
// one v_perm_b32: [hi16(b+rnd) : hi16(a+rnd)]
static __device__ __forceinline__ unsigned int pack2rn(float a, float b) {
    union { float f; unsigned int u; } ca, cb; ca.f = a; cb.f = b;
    return __builtin_amdgcn_perm(cb.u + 0x8000u, ca.u + 0x8000u, 0x07060302u);
}
static __device__ __forceinline__ float bflo(unsigned int u) {
    union { unsigned int x; float f; } c; c.x = u << 16; return c.f;
}
static __device__ __forceinline__ float bfhi(unsigned int u) {
    union { unsigned int x; float f; } c; c.x = u & 0xFFFF0000u; return c.f;
}
static __device__ __forceinline__ f32x4 mfma16(uint4 a, uint4 b, f32x4 c) {
    return __builtin_amdgcn_mfma_f32_16x16x32_bf16(
        __builtin_bit_cast(bf16x8, a), __builtin_bit_cast(bf16x8, b), c, 0, 0, 0);
}
static __device__ __forceinline__ void gl_lds16(const unsigned short* g, unsigned short* l) {
    __builtin_amdgcn_global_load_lds(
        (const __attribute__((address_space(1))) unsigned int*)g,
        (__attribute__((address_space(3))) unsigned int*)l, 16, 0, 0);
}

// ---------------- fp32 -> bf16 copy (x and W matrices) ----------------
__global__ __launch_bounds__(256) void cvt_k(const float* __restrict__ x,
                                             unsigned short* __restrict__ xb)
{
    size_t i = ((size_t)blockIdx.x * 256 + threadIdx.x) * 8;
    float4 a = *(const float4*)(x + i);
    float4 b = *(const float4*)(x + i + 4);
    uint4 p = { pack2(a.x, a.y), pack2(a.z, a.w), pack2(b.x, b.y), pack2(b.z, b.w) };
    *(uint4*)(xb + i) = p;
}

// ---------------- proj GEMM: out[m,n] = sum_k A[m,k]*Wb[n,k] + bias[n] ----------------
// A bf16 [4096][1024], Wb bf16 [1024][1024]; both staged via global_load_lds.
// BM=128 BN=64 BK=64, 4 waves, grid(16,32)=512 blocks.
// MODE 0: per-head bf16 out[((b*16+h)*2048+q)*64+d]  (h=n>>6, d=n&63)
// MODE 1: bf16 Vt[(b*1024+n)*2048+s] via LDS transpose (dense stores)
template <int MODE>
__global__ __launch_bounds__(256) void gemm_qkv(
    const unsigned short* __restrict__ A, const unsigned short* __restrict__ Wb,
    const float* __restrict__ bias, unsigned short* __restrict__ out)
{
    __shared__ unsigned short lA[128 * 64];  // 16 KB
    __shared__ unsigned short lB[64 * 64];   // 8 KB
    const int tid = threadIdx.x;
    const int wv = tid >> 6, lane = tid & 63, quad = lane >> 4, lm = lane & 15;
    const int m0 = blockIdx.y * 128, n0 = blockIdx.x * 64;
    const int sub = lane >> 3, chl = (lane & 7) ^ sub;

    f32x4 acc[2][4] = {};

    for (int k0 = 0; k0 < D_MODEL; k0 += 64) {
        __syncthreads();
#pragma unroll
        for (int j = 0; j < 4; ++j) {  // A: 128 rows
            int rbase = wv * 32 + j * 8;
            gl_lds16(A + (size_t)(m0 + rbase + sub) * D_MODEL + k0 + chl * 8,
                     &lA[rbase * 64]);
        }
#pragma unroll
        for (int j = 0; j < 2; ++j) {  // B: 64 rows
            int rbase = wv * 16 + j * 8;
            gl_lds16(Wb + (size_t)(n0 + rbase + sub) * D_MODEL + k0 + chl * 8,
                     &lB[rbase * 64]);
        }
        __syncthreads();
#pragma unroll
        for (int ks = 0; ks < 2; ++ks) {
            uint4 af[2];
#pragma unroll
            for (int mt = 0; mt < 2; ++mt)
                af[mt] = *(const uint4*)&lA[(wv * 32 + mt * 16 + lm) * 64 +
                                            ((ks * 4 + quad) ^ (lm & 7)) * 8];
#pragma unroll
            for (int nt = 0; nt < 4; ++nt) {
                uint4 bf = *(const uint4*)&lB[(nt * 16 + lm) * 64 +
                                              ((ks * 4 + quad) ^ (lm & 7)) * 8];
                acc[0][nt] = mfma16(af[0], bf, acc[0][nt]);
                acc[1][nt] = mfma16(af[1], bf, acc[1][nt]);
            }
        }
    }

    if (MODE == 0) {
        const int h = n0 >> 6;
#pragma unroll
        for (int nt = 0; nt < 4; ++nt) {
            float bv = bias[n0 + nt * 16 + lm];
            int d = nt * 16 + lm;
#pragma unroll
            for (int mt = 0; mt < 2; ++mt)
#pragma unroll
                for (int r = 0; r < 4; ++r) {
                    int m = m0 + wv * 32 + mt * 16 + quad * 4 + r;
                    int b = m >> 11, q = m & 2047;
                    out[((size_t)(b * NH + h) * SEQ + q) * DKH + d] =
                        f2bf(acc[mt][nt][r] + bv);
                }
        }
    } else {
        // transpose through LDS: T[64 n][128 m] u16 over lA
        __syncthreads();
        unsigned short* T = lA;
#pragma unroll
        for (int nt = 0; nt < 4; ++nt) {
            float bv = bias[n0 + nt * 16 + lm];
            int nl = nt * 16 + lm;
#pragma unroll
            for (int mt = 0; mt < 2; ++mt) {
                int ml = wv * 32 + mt * 16 + quad * 4;
                uint2 p = { pack2rn(acc[mt][nt][0] + bv, acc[mt][nt][1] + bv),
                            pack2rn(acc[mt][nt][2] + bv, acc[mt][nt][3] + bv) };
                *(uint2*)&T[nl * 128 + ml] = p;
            }
        }
        __syncthreads();
        int row = tid >> 2, seg = tid & 3;
        int b = m0 >> 11, s0 = m0 & 2047;
        unsigned short* dst = out + ((size_t)(b * D_MODEL) + n0 + row) * SEQ + s0 + seg * 32;
        const unsigned short* src = &T[row * 128 + seg * 32];
#pragma unroll
        for (int i = 0; i < 4; ++i)
            *(uint4*)(dst + i * 8) = *(const uint4*)(src + i * 8);
    }
}

// ---------------- out-proj: ctx = sum of KS per-head partials; fp32 out ----------------
template <int KS>
__global__ __launch_bounds__(256) void gemm_osum(
    const unsigned short* __restrict__ OP, const float* __restrict__ W,
    const float* __restrict__ bias, float* __restrict__ out)
{
    __shared__ unsigned short lA[128 * 64];
    __shared__ unsigned short lB[64 * 64];
    const int tid = threadIdx.x;
    const int wv = tid >> 6, lane = tid & 63, quad = lane >> 4, lm = lane & 15;
    const int m0 = blockIdx.y * 128, n0 = blockIdx.x * 64;
    const size_t M = (size_t)NTOK * D_MODEL;
    const int brow = tid >> 2, bpart = tid & 3;

    f32x4 acc[2][4] = {};

    for (int k0 = 0; k0 < D_MODEL; k0 += 64) {
        const int h = k0 >> 6;
        __syncthreads();
#pragma unroll
        for (int r = 0; r < 4; ++r) {  // A: 128 rows x 8 chunks
            int idx = r * 256 + tid;
            int row = idx >> 3, ch = idx & 7, phys = ch ^ (row & 7);
            int m = m0 + row, b = m >> 11, q = m & 2047;
            size_t base = ((size_t)(b * NH + h) * SEQ + q) * DKH + ch * 8;
            uint4 u = *(const uint4*)(OP + base);
            float lo0 = bflo(u.x), hi0 = bfhi(u.x), lo1 = bflo(u.y), hi1 = bfhi(u.y);
            float lo2 = bflo(u.z), hi2 = bfhi(u.z), lo3 = bflo(u.w), hi3 = bfhi(u.w);
#pragma unroll
            for (int p = 1; p < KS; ++p) {
                uint4 v = *(const uint4*)(OP + p * M + base);
                lo0 += bflo(v.x); hi0 += bfhi(v.x); lo1 += bflo(v.y); hi1 += bfhi(v.y);
                lo2 += bflo(v.z); hi2 += bfhi(v.z); lo3 += bflo(v.w); hi3 += bfhi(v.w);
            }
            uint4 pa = { pack2(lo0, hi0), pack2(lo1, hi1), pack2(lo2, hi2), pack2(lo3, hi3) };
            *(uint4*)&lA[row * 64 + phys * 8] = pa;
        }
        {   // B: fp32 W converted
            const float* gb = W + (size_t)(n0 + brow) * D_MODEL + k0 + bpart * 16;
            float4 f0 = *(const float4*)gb;
            float4 f1 = *(const float4*)(gb + 4);
            float4 f2 = *(const float4*)(gb + 8);
            float4 f3 = *(const float4*)(gb + 12);
            uint4 p0 = { pack2(f0.x, f0.y), pack2(f0.z, f0.w), pack2(f1.x, f1.y), pack2(f1.z, f1.w) };
            uint4 p1 = { pack2(f2.x, f2.y), pack2(f2.z, f2.w), pack2(f3.x, f3.y), pack2(f3.z, f3.w) };
            int c0 = (bpart * 2) ^ (brow & 7), c1 = (bpart * 2 + 1) ^ (brow & 7);
            *(uint4*)&lB[brow * 64 + c0 * 8] = p0;
            *(uint4*)&lB[brow * 64 + c1 * 8] = p1;
        }
        __syncthreads();
#pragma unroll
        for (int ks = 0; ks < 2; ++ks) {
            uint4 af[2];
#pragma unroll
            for (int mt = 0; mt < 2; ++mt)
                af[mt] = *(const uint4*)&lA[(wv * 32 + mt * 16 + lm) * 64 +
                                            ((ks * 4 + quad) ^ (lm & 7)) * 8];
#pragma unroll
            for (int nt = 0; nt < 4; ++nt) {
                uint4 bf = *(const uint4*)&lB[(nt * 16 + lm) * 64 +
                                              ((ks * 4 + quad) ^ (lm & 7)) * 8];
                acc[0][nt] = mfma16(af[0], bf, acc[0][nt]);
                acc[1][nt] = mfma16(af[1], bf, acc[1][nt]);
            }
        }
    }
#pragma unroll
    for (int nt = 0; nt < 4; ++nt) {
        int n = n0 + nt * 16 + lm;
        float bv = bias[n];
#pragma unroll
        for (int mt = 0; mt < 2; ++mt)
#pragma unroll
            for (int r = 0; r < 4; ++r) {
                int m = m0 + wv * 32 + mt * 16 + quad * 4 + r;
                out[(size_t)m * D_MODEL + n] = acc[mt][nt][r] + bv;
            }
    }
}

// ---------------- rz[b][q][k] = 1/sum_h exp(S_h[q,k]*scale) ----------------
// Per-head Qh/Kh: all loads are dense 2KB regions. Z per-lane in C-layout.
__global__ __launch_bounds__(256, 4) void zker(
    const unsigned short* __restrict__ Qh, const unsigned short* __restrict__ Kh,
    unsigned short* __restrict__ rz)
{
    const int tid = threadIdx.x;
    const int wv = tid >> 6, lane = tid & 63, quad = lane >> 4, lm = lane & 15;
    const int kb = blockIdx.x, qb = blockIdx.y, b = blockIdx.z;
    const int q0w = qb * 64 + wv * 16;
    const int k0 = kb * 64;
    const size_t HS = (size_t)SEQ * DKH;

    const unsigned short* qrow = Qh + ((size_t)(b * NH) * SEQ + q0w + lm) * DKH + quad * 8;
    const unsigned short* krow = Kh + ((size_t)(b * NH) * SEQ + k0 + lm) * DKH + quad * 8;

    f32x4 z[4] = {};

#pragma unroll
    for (int h = 0; h < NH; ++h) {
        const unsigned short* qh = qrow + h * HS;
        uint4 af0 = *(const uint4*)qh;
        uint4 af1 = *(const uint4*)(qh + 32);
#pragma unroll
        for (int ksub = 0; ksub < 4; ++ksub) {
            const unsigned short* kr = krow + h * HS + (size_t)ksub * 16 * DKH;
            uint4 bf0 = *(const uint4*)kr;
            uint4 bf1 = *(const uint4*)(kr + 32);
            f32x4 sf = {0.f, 0.f, 0.f, 0.f};
            sf = mfma16(af0, bf0, sf);
            sf = mfma16(af1, bf1, sf);
#pragma unroll
            for (int r = 0; r < 4; ++r)
                z[ksub][r] += __expf(sf[r] * SCALE);
        }
    }
#pragma unroll
    for (int ksub = 0; ksub < 4; ++ksub)
#pragma unroll
        for (int r = 0; r < 4; ++r)
            rz[(size_t)(b * SEQ + q0w + quad * 4 + r) * SEQ + k0 + ksub * 16 + lm] =
                f2bf(1.0f / z[ksub][r]);
}

// ---------------- per-head attention, software-pipelined ----------------
template <int KS>
__global__ __launch_bounds__(256, 2) void attn2(
    const unsigned short* __restrict__ Qh, const unsigned short* __restrict__ Kh,
    const unsigned short* __restrict__ Vt, const unsigned short* __restrict__ rz,
    unsigned short* __restrict__ OP)
{
    const int tid = threadIdx.x;
    const int wv = tid >> 6, lane = tid & 63, quad = lane >> 4, lm = lane & 15;
    const int qb = blockIdx.x;
    const int bh = blockIdx.y, b = bh >> 4, h = bh & 15;
    const int ksl = blockIdx.z;
    const int NIT = (SEQ / KS) / 32;
    const int kbeg = ksl * (SEQ / KS);
    const int q0w = qb * 128 + wv * 32;
    const size_t hb = (size_t)(b * NH + h) * SEQ;

    uint4 qf[2][2];
#pragma unroll
    for (int qs = 0; qs < 2; ++qs)
#pragma unroll
        for (int ks = 0; ks < 2; ++ks)
            qf[qs][ks] = *(const uint4*)(Qh + (hb + q0w + qs * 16 + lm) * DKH +
                                         ks * 32 + quad * 8);

    const int perm = ((lm >> 2) * 8) + (lm & 3);
    const unsigned short* kp = Kh + (hb + kbeg + perm) * DKH + quad * 8;
    const unsigned short* vp = Vt + ((size_t)(b * D_MODEL) + h * DKH + lm) * SEQ + kbeg + quad * 8;
    const unsigned short* rp = rz + ((size_t)(b * SEQ) + q0w + lm) * SEQ + kbeg + quad * 8;

    f32x4 oa[4][2] = {};
    uint4 kf[2][2][2];
    uint4 rv[2][2];

    // prefetch iter 0
#pragma unroll
    for (int sel = 0; sel < 2; ++sel)
#pragma unroll
        for (int ks = 0; ks < 2; ++ks)
            kf[0][sel][ks] = *(const uint4*)(kp + (size_t)(sel * 4) * DKH + ks * 32);
#pragma unroll
    for (int qs = 0; qs < 2; ++qs)
        rv[0][qs] = *(const uint4*)(rp + (size_t)qs * 16 * SEQ);

#pragma unroll
    for (int kt = 0; kt < NIT; ++kt) {
        const int cur = kt & 1, nxt = cur ^ 1;
        if (kt + 1 < NIT) {
#pragma unroll
            for (int sel = 0; sel < 2; ++sel)
#pragma unroll
                for (int ks = 0; ks < 2; ++ks)
                    kf[nxt][sel][ks] = *(const uint4*)(kp +
                        (size_t)((kt + 1) * 32 + sel * 4) * DKH + ks * 32);
#pragma unroll
            for (int qs = 0; qs < 2; ++qs)
                rv[nxt][qs] = *(const uint4*)(rp + (size_t)qs * 16 * SEQ + (kt + 1) * 32);
        }
        // V early (consumed last)
        uint4 vf[4];
#pragma unroll
        for (int ct = 0; ct < 4; ++ct)
            vf[ct] = *(const uint4*)(vp + (size_t)ct * 16 * SEQ + kt * 32);

        f32x4 sf[2][2] = {};
#pragma unroll
        for (int sel = 0; sel < 2; ++sel)
#pragma unroll
            for (int qs = 0; qs < 2; ++qs)
#pragma unroll
                for (int ks = 0; ks < 2; ++ks)
                    sf[sel][qs] = mfma16(kf[cur][sel][ks], qf[qs][ks], sf[sel][qs]);

        uint4 pk[2];
#pragma unroll
        for (int qs = 0; qs < 2; ++qs) {
            uint4 rq = rv[cur][qs];
            float p00 = __expf(sf[0][qs][0] * SCALE) * bflo(rq.x);
            float p01 = __expf(sf[0][qs][1] * SCALE) * bfhi(rq.x);
            float p02 = __expf(sf[0][qs][2] * SCALE) * bflo(rq.y);
            float p03 = __expf(sf[0][qs][3] * SCALE) * bfhi(rq.y);
            float p10 = __expf(sf[1][qs][0] * SCALE) * bflo(rq.z);
            float p11 = __expf(sf[1][qs][1] * SCALE) * bfhi(rq.z);
            float p12 = __expf(sf[1][qs][2] * SCALE) * bflo(rq.w);
            float p13 = __expf(sf[1][qs][3] * SCALE) * bfhi(rq.w);
            pk[qs].x = pack2rn(p00, p01);
            pk[qs].y = pack2rn(p02, p03);
            pk[qs].z = pack2rn(p10, p11);
            pk[qs].w = pack2rn(p12, p13);
        }
#pragma unroll
        for (int ct = 0; ct < 4; ++ct) {
            oa[ct][0] = mfma16(vf[ct], pk[0], oa[ct][0]);
            oa[ct][1] = mfma16(vf[ct], pk[1], oa[ct][1]);
        }
    }

    unsigned short* op = OP + (size_t)ksl * NTOK * D_MODEL;
#pragma unroll
    for (int ct = 0; ct < 4; ++ct)
#pragma unroll
        for (int qs = 0; qs < 2; ++qs) {
            uint2 st = { pack2rn(oa[ct][qs][0], oa[ct][qs][1]),
                         pack2rn(oa[ct][qs][2], oa[ct][qs][3]) };
            *(uint2*)(op + (hb + q0w + qs * 16 + lm) * DKH + ct * 16 + quad * 4) = st;
        }
}

extern "C" void kernel_launch(void* const* d_in, const int* in_sizes, int n_in,
                              void* d_out, int out_size, void* d_ws, size_t ws_size,
                              hipStream_t stream)
{
    const float* x  = (const float*)d_in[0];
    const float* Wq = (const float*)d_in[1];
    const float* bq = (const float*)d_in[2];
    const float* Wk = (const float*)d_in[3];
    const float* bk = (const float*)d_in[4];
    const float* Wv = (const float*)d_in[5];
    const float* bv = (const float*)d_in[6];
    const float* Wo = (const float*)d_in[7];
    const float* bo = (const float*)d_in[8];
    float* out = (float*)d_out;

    const size_t M  = (size_t)NTOK * D_MODEL;      // 4,194,304
    const size_t RZ = (size_t)NB * SEQ * SEQ;      // 8,388,608
    const size_t WE = (size_t)D_MODEL * D_MODEL;   // 1,048,576
    unsigned short* ws = (unsigned short*)d_ws;
    unsigned short* xb  = ws;            // bf16 x; aliased by rz (xb dead after projs)
    unsigned short* rzb = ws;
    unsigned short* Qh  = ws + RZ;       // per-head [(b,h,q)][dk]
    unsigned short* Kh  = Qh + M;
    unsigned short* Vt  = Kh + M;        // [b][c][s]
    unsigned short* OP  = Vt + M;        // KS per-head partials;早期 aliased by Wb
    unsigned short* WbQ = OP;            // bf16 weights (dead before attn2 writes OP)
    unsigned short* WbK = OP + WE;
    unsigned short* WbV = OP + 2 * WE;

    const size_t need4 = (RZ + 3 * M + 4 * M) * sizeof(unsigned short);  // 75.5 MB
    const size_t need2 = (RZ + 3 * M + 2 * M) * sizeof(unsigned short);  // 58.7 MB
    const int KS = (ws_size >= need4) ? 4 : (ws_size >= need2) ? 2 : 1;

    cvt_k<<<2048, 256, 0, stream>>>(x, xb);
    cvt_k<<<512, 256, 0, stream>>>(Wq, WbQ);
    cvt_k<<<512, 256, 0, stream>>>(Wk, WbK);
    cvt_k<<<512, 256, 0, stream>>>(Wv, WbV);
    dim3 gg(16, 32);
    gemm_qkv<0><<<gg, 256, 0, stream>>>(xb, WbQ, bq, Qh);
    gemm_qkv<0><<<gg, 256, 0, stream>>>(xb, WbK, bk, Kh);
    gemm_qkv<1><<<gg, 256, 0, stream>>>(xb, WbV, bv, Vt);
    zker<<<dim3(32, 32, NB), 256, 0, stream>>>(Qh, Kh, rzb);
    if (KS == 4) {
        attn2<4><<<dim3(16, NB * NH, 4), 256, 0, stream>>>(Qh, Kh, Vt, rzb, OP);
        gemm_osum<4><<<gg, 256, 0, stream>>>(OP, Wo, bo, out);
    } else if (KS == 2) {
        attn2<2><<<dim3(16, NB * NH, 2), 256, 0, stream>>>(Qh, Kh, Vt, rzb, OP);
        gemm_osum<2><<<gg, 256, 0, stream>>>(OP, Wo, bo, out);
    } else {
        attn2<1><<<dim3(16, NB * NH, 1), 256, 0, stream>>>(Qh, Kh, Vt, rzb, OP);
        gemm_osum<1><<<gg, 256, 0, stream>>>(OP, Wo, bo, out);
    }
}

// Round 6
// 305.191 us; speedup vs baseline: 1.7338x; 1.7338x over previous
//
#include <hip/hip_runtime.h>

// MultiHeadattention: B=2, S=2048, D=1024, H=16, Dk=64.
// QUIRK: softmax over the HEAD axis (dim=1): attn[b,h,q,k] = exp(s)/sum_h' exp(s').
// R6: attention kernels restructured to m97-style global_load_lds staging:
//   zker2: block (128q x 128k, b); per h: stage Q/K h-slabs (16+16 KB) -> 32 MFMA/wave;
//          rz = 1/sum_h exp;  A=K,B=Q orientation -> uint2 rz stores.
//   attn3: block (128q, b, h, ksl); per 64-key iter stage K(8K)+Vt(8K)+rz(16K);
//          4 waves share tiles (4x less K/V traffic than R5's per-wave loads).
// LDS swizzle everywhere: chunk ^ ((row&7)^((row>>2)&7)) -> <=2-way conflicts (free).

#define D_MODEL 1024
#define NH 16
#define DKH 64
#define SEQ 2048
#define NB 2
#define NTOK (NB * SEQ)
#define SCALE 0.125f

typedef float f32x4 __attribute__((ext_vector_type(4)));
typedef short bf16x8 __attribute__((ext_vector_type(8)));

static __device__ __forceinline__ unsigned short f2bf(float x) {
    union { float f; unsigned int u; } c; c.f = x;
    unsigned int r = (c.u + 0x7FFFu + ((c.u >> 16) & 1u)) >> 16;
    return (unsigned short)r;
}
static __device__ __forceinline__ unsigned int pack2(float a, float b) {
    return (unsigned int)f2bf(a) | ((unsigned int)f2bf(b) << 16);
}
static __device__ __forceinline__ unsigned int pack2rn(float a, float b) {
    union { float f; unsigned int u; } ca, cb; ca.f = a; cb.f = b;
    return __builtin_amdgcn_perm(cb.u + 0x8000u, ca.u + 0x8000u, 0x07060302u);
}
static __device__ __forceinline__ float bflo(unsigned int u) {
    union { unsigned int x; float f; } c; c.x = u << 16; return c.f;
}
static __device__ __forceinline__ float bfhi(unsigned int u) {
    union { unsigned int x; float f; } c; c.x = u & 0xFFFF0000u; return c.f;
}
static __device__ __forceinline__ f32x4 mfma16(uint4 a, uint4 b, f32x4 c) {
    return __builtin_amdgcn_mfma_f32_16x16x32_bf16(
        __builtin_bit_cast(bf16x8, a), __builtin_bit_cast(bf16x8, b), c, 0, 0, 0);
}
static __device__ __forceinline__ void gl_lds16(const unsigned short* g, unsigned short* l) {
    __builtin_amdgcn_global_load_lds(
        (const __attribute__((address_space(1))) unsigned int*)g,
        (__attribute__((address_space(3))) unsigned int*)l, 16, 0, 0);
}
static __device__ __forceinline__ int fsw(int row) {
    return (row & 7) ^ ((row >> 2) & 7);
}

// ---------------- fp32 -> bf16 copy ----------------
__global__ __launch_bounds__(256) void cvt_k(const float* __restrict__ x,
                                             unsigned short* __restrict__ xb)
{
    size_t i = ((size_t)blockIdx.x * 256 + threadIdx.x) * 8;
    float4 a = *(const float4*)(x + i);
    float4 b = *(const float4*)(x + i + 4);
    uint4 p = { pack2(a.x, a.y), pack2(a.z, a.w), pack2(b.x, b.y), pack2(b.z, b.w) };
    *(uint4*)(xb + i) = p;
}

// ---------------- proj GEMM (unchanged from R5) ----------------
template <int MODE>
__global__ __launch_bounds__(256) void gemm_qkv(
    const unsigned short* __restrict__ A, const unsigned short* __restrict__ Wb,
    const float* __restrict__ bias, unsigned short* __restrict__ out)
{
    __shared__ unsigned short lA[128 * 64];
    __shared__ unsigned short lB[64 * 64];
    const int tid = threadIdx.x;
    const int wv = tid >> 6, lane = tid & 63, quad = lane >> 4, lm = lane & 15;
    const int m0 = blockIdx.y * 128, n0 = blockIdx.x * 64;
    const int sub = lane >> 3, chl = (lane & 7) ^ sub;

    f32x4 acc[2][4] = {};

    for (int k0 = 0; k0 < D_MODEL; k0 += 64) {
        __syncthreads();
#pragma unroll
        for (int j = 0; j < 4; ++j) {
            int rbase = wv * 32 + j * 8;
            gl_lds16(A + (size_t)(m0 + rbase + sub) * D_MODEL + k0 + chl * 8,
                     &lA[rbase * 64]);
        }
#pragma unroll
        for (int j = 0; j < 2; ++j) {
            int rbase = wv * 16 + j * 8;
            gl_lds16(Wb + (size_t)(n0 + rbase + sub) * D_MODEL + k0 + chl * 8,
                     &lB[rbase * 64]);
        }
        __syncthreads();
#pragma unroll
        for (int ks = 0; ks < 2; ++ks) {
            uint4 af[2];
#pragma unroll
            for (int mt = 0; mt < 2; ++mt)
                af[mt] = *(const uint4*)&lA[(wv * 32 + mt * 16 + lm) * 64 +
                                            ((ks * 4 + quad) ^ (lm & 7)) * 8];
#pragma unroll
            for (int nt = 0; nt < 4; ++nt) {
                uint4 bf = *(const uint4*)&lB[(nt * 16 + lm) * 64 +
                                              ((ks * 4 + quad) ^ (lm & 7)) * 8];
                acc[0][nt] = mfma16(af[0], bf, acc[0][nt]);
                acc[1][nt] = mfma16(af[1], bf, acc[1][nt]);
            }
        }
    }

    if (MODE == 0) {
        const int h = n0 >> 6;
#pragma unroll
        for (int nt = 0; nt < 4; ++nt) {
            float bv = bias[n0 + nt * 16 + lm];
            int d = nt * 16 + lm;
#pragma unroll
            for (int mt = 0; mt < 2; ++mt)
#pragma unroll
                for (int r = 0; r < 4; ++r) {
                    int m = m0 + wv * 32 + mt * 16 + quad * 4 + r;
                    int b = m >> 11, q = m & 2047;
                    out[((size_t)(b * NH + h) * SEQ + q) * DKH + d] =
                        f2bf(acc[mt][nt][r] + bv);
                }
        }
    } else {
        __syncthreads();
        unsigned short* T = lA;
#pragma unroll
        for (int nt = 0; nt < 4; ++nt) {
            float bv = bias[n0 + nt * 16 + lm];
            int nl = nt * 16 + lm;
#pragma unroll
            for (int mt = 0; mt < 2; ++mt) {
                int ml = wv * 32 + mt * 16 + quad * 4;
                uint2 p = { pack2rn(acc[mt][nt][0] + bv, acc[mt][nt][1] + bv),
                            pack2rn(acc[mt][nt][2] + bv, acc[mt][nt][3] + bv) };
                *(uint2*)&T[nl * 128 + ml] = p;
            }
        }
        __syncthreads();
        int row = tid >> 2, seg = tid & 3;
        int b = m0 >> 11, s0 = m0 & 2047;
        unsigned short* dst = out + ((size_t)(b * D_MODEL) + n0 + row) * SEQ + s0 + seg * 32;
        const unsigned short* src = &T[row * 128 + seg * 32];
#pragma unroll
        for (int i = 0; i < 4; ++i)
            *(uint4*)(dst + i * 8) = *(const uint4*)(src + i * 8);
    }
}

// ---------------- out-proj (unchanged from R5) ----------------
template <int KS>
__global__ __launch_bounds__(256) void gemm_osum(
    const unsigned short* __restrict__ OP, const float* __restrict__ W,
    const float* __restrict__ bias, float* __restrict__ out)
{
    __shared__ unsigned short lA[128 * 64];
    __shared__ unsigned short lB[64 * 64];
    const int tid = threadIdx.x;
    const int wv = tid >> 6, lane = tid & 63, quad = lane >> 4, lm = lane & 15;
    const int m0 = blockIdx.y * 128, n0 = blockIdx.x * 64;
    const size_t M = (size_t)NTOK * D_MODEL;
    const int brow = tid >> 2, bpart = tid & 3;

    f32x4 acc[2][4] = {};

    for (int k0 = 0; k0 < D_MODEL; k0 += 64) {
        const int h = k0 >> 6;
        __syncthreads();
#pragma unroll
        for (int r = 0; r < 4; ++r) {
            int idx = r * 256 + tid;
            int row = idx >> 3, ch = idx & 7, phys = ch ^ (row & 7);
            int m = m0 + row, b = m >> 11, q = m & 2047;
            size_t base = ((size_t)(b * NH + h) * SEQ + q) * DKH + ch * 8;
            uint4 u = *(const uint4*)(OP + base);
            float lo0 = bflo(u.x), hi0 = bfhi(u.x), lo1 = bflo(u.y), hi1 = bfhi(u.y);
            float lo2 = bflo(u.z), hi2 = bfhi(u.z), lo3 = bflo(u.w), hi3 = bfhi(u.w);
#pragma unroll
            for (int p = 1; p < KS; ++p) {
                uint4 v = *(const uint4*)(OP + p * M + base);
                lo0 += bflo(v.x); hi0 += bfhi(v.x); lo1 += bflo(v.y); hi1 += bfhi(v.y);
                lo2 += bflo(v.z); hi2 += bfhi(v.z); lo3 += bflo(v.w); hi3 += bfhi(v.w);
            }
            uint4 pa = { pack2(lo0, hi0), pack2(lo1, hi1), pack2(lo2, hi2), pack2(lo3, hi3) };
            *(uint4*)&lA[row * 64 + phys * 8] = pa;
        }
        {
            const float* gb = W + (size_t)(n0 + brow) * D_MODEL + k0 + bpart * 16;
            float4 f0 = *(const float4*)gb;
            float4 f1 = *(const float4*)(gb + 4);
            float4 f2 = *(const float4*)(gb + 8);
            float4 f3 = *(const float4*)(gb + 12);
            uint4 p0 = { pack2(f0.x, f0.y), pack2(f0.z, f0.w), pack2(f1.x, f1.y), pack2(f1.z, f1.w) };
            uint4 p1 = { pack2(f2.x, f2.y), pack2(f2.z, f2.w), pack2(f3.x, f3.y), pack2(f3.z, f3.w) };
            int c0 = (bpart * 2) ^ (brow & 7), c1 = (bpart * 2 + 1) ^ (brow & 7);
            *(uint4*)&lB[brow * 64 + c0 * 8] = p0;
            *(uint4*)&lB[brow * 64 + c1 * 8] = p1;
        }
        __syncthreads();
#pragma unroll
        for (int ks = 0; ks < 2; ++ks) {
            uint4 af[2];
#pragma unroll
            for (int mt = 0; mt < 2; ++mt)
                af[mt] = *(const uint4*)&lA[(wv * 32 + mt * 16 + lm) * 64 +
                                            ((ks * 4 + quad) ^ (lm & 7)) * 8];
#pragma unroll
            for (int nt = 0; nt < 4; ++nt) {
                uint4 bf = *(const uint4*)&lB[(nt * 16 + lm) * 64 +
                                              ((ks * 4 + quad) ^ (lm & 7)) * 8];
                acc[0][nt] = mfma16(af[0], bf, acc[0][nt]);
                acc[1][nt] = mfma16(af[1], bf, acc[1][nt]);
            }
        }
    }
#pragma unroll
    for (int nt = 0; nt < 4; ++nt) {
        int n = n0 + nt * 16 + lm;
        float bv = bias[n];
#pragma unroll
        for (int mt = 0; mt < 2; ++mt)
#pragma unroll
            for (int r = 0; r < 4; ++r) {
                int m = m0 + wv * 32 + mt * 16 + quad * 4 + r;
                out[(size_t)m * D_MODEL + n] = acc[mt][nt][r] + bv;
            }
    }
}

// ---------------- zker2: rz[b][q][k] = 1/sum_h exp(S*scale), LDS-staged ----------------
// Block: 128q x 128k, batch b. Loop h: stage Q/K h-slabs (16+16 KB) via global_load_lds.
// A=K (m=k), B=Q (n=q): C lane holds q=lm (col), k=quad*4+r (row) -> uint2 stores.
__global__ __launch_bounds__(256) void zker2(
    const unsigned short* __restrict__ Qh, const unsigned short* __restrict__ Kh,
    unsigned short* __restrict__ rz)
{
    __shared__ unsigned short lQ[128 * 64];  // 16 KB
    __shared__ unsigned short lK[128 * 64];  // 16 KB
    const int tid = threadIdx.x;
    const int wv = tid >> 6, lane = tid & 63, quad = lane >> 4, lm = lane & 15;
    const int q0 = blockIdx.x * 128, k0 = blockIdx.y * 128, b = blockIdx.z;
    const int srow = tid >> 3, sc = tid & 7;

    f32x4 z[2][8] = {};

    for (int h = 0; h < NH; ++h) {
        const size_t qb = ((size_t)(b * NH + h) * SEQ + q0) * DKH;
        const size_t kb = ((size_t)(b * NH + h) * SEQ + k0) * DKH;
        __syncthreads();
#pragma unroll
        for (int j = 0; j < 4; ++j) {
            int row = j * 32 + srow;
            int g = sc ^ fsw(row);
            gl_lds16(Qh + qb + (size_t)row * 64 + g * 8, &lQ[(j * 32 + wv * 8) * 64]);
            gl_lds16(Kh + kb + (size_t)row * 64 + g * 8, &lK[(j * 32 + wv * 8) * 64]);
        }
        __syncthreads();

        uint4 bq[2][2];
#pragma unroll
        for (int qs = 0; qs < 2; ++qs) {
            int qrow = wv * 32 + qs * 16 + lm;
#pragma unroll
            for (int ks = 0; ks < 2; ++ks)
                bq[qs][ks] = *(const uint4*)&lQ[qrow * 64 +
                                                ((ks * 4 + quad) ^ fsw(qrow)) * 8];
        }
#pragma unroll
        for (int kt = 0; kt < 8; ++kt) {
            int krow = kt * 16 + lm;
            uint4 a0 = *(const uint4*)&lK[krow * 64 + ((quad) ^ fsw(krow)) * 8];
            uint4 a1 = *(const uint4*)&lK[krow * 64 + ((4 + quad) ^ fsw(krow)) * 8];
#pragma unroll
            for (int qs = 0; qs < 2; ++qs) {
                f32x4 sf = {0.f, 0.f, 0.f, 0.f};
                sf = mfma16(a0, bq[qs][0], sf);
                sf = mfma16(a1, bq[qs][1], sf);
#pragma unroll
                for (int r = 0; r < 4; ++r)
                    z[qs][kt][r] += __expf(sf[r] * SCALE);
            }
        }
    }
#pragma unroll
    for (int qs = 0; qs < 2; ++qs) {
        int q = q0 + wv * 32 + qs * 16 + lm;
#pragma unroll
        for (int kt = 0; kt < 8; ++kt) {
            int k = k0 + kt * 16 + quad * 4;
            uint2 st = { pack2rn(1.0f / z[qs][kt][0], 1.0f / z[qs][kt][1]),
                         pack2rn(1.0f / z[qs][kt][2], 1.0f / z[qs][kt][3]) };
            *(uint2*)(rz + (size_t)(b * SEQ + q) * SEQ + k) = st;
        }
    }
}

// ---------------- attn3: per-head attention, LDS-staged K/Vt/rz ----------------
// Block: (qb 128, b*16+h, ksl). Tk=64/iter: stage K 8KB + Vt 8KB + rz 16KB,
// shared by 4 waves. Perm-trick S^T -> pk (K=32 B-frag) -> PV, as proven in R3.
template <int KS>
__global__ __launch_bounds__(256) void attn3(
    const unsigned short* __restrict__ Qh, const unsigned short* __restrict__ Kh,
    const unsigned short* __restrict__ Vt, const unsigned short* __restrict__ rz,
    unsigned short* __restrict__ OP)
{
    __shared__ unsigned short lK[64 * 64];    // 8 KB
    __shared__ unsigned short lV[64 * 64];    // 8 KB
    __shared__ unsigned short lrz[128 * 64];  // 16 KB
    const int tid = threadIdx.x;
    const int wv = tid >> 6, lane = tid & 63, quad = lane >> 4, lm = lane & 15;
    const int q0 = blockIdx.x * 128;
    const int bh = blockIdx.y, b = bh >> 4, h = bh & 15;
    const int ksl = blockIdx.z;
    const int NIT = (SEQ / KS) / 64;
    const int kbeg = ksl * (SEQ / KS);
    const int q0w = q0 + wv * 32;
    const size_t hb = (size_t)(b * NH + h) * SEQ;
    const int srow = tid >> 3, sc = tid & 7;

    uint4 qf[2][2];
#pragma unroll
    for (int qs = 0; qs < 2; ++qs)
#pragma unroll
        for (int ks = 0; ks < 2; ++ks)
            qf[qs][ks] = *(const uint4*)(Qh + (hb + q0w + qs * 16 + lm) * DKH +
                                         ks * 32 + quad * 8);

    const int perm = ((lm >> 2) * 8) + (lm & 3);
    f32x4 oa[4][2] = {};

    for (int kt = 0; kt < NIT; ++kt) {
        const int kbase = kbeg + kt * 64;
        __syncthreads();
#pragma unroll
        for (int j = 0; j < 2; ++j) {   // K tile: 64 keys x 128 B (contiguous slab)
            int row = j * 32 + srow;
            int g = sc ^ fsw(row);
            gl_lds16(Kh + (hb + kbase + row) * DKH + g * 8,
                     &lK[(j * 32 + wv * 8) * 64]);
        }
#pragma unroll
        for (int j = 0; j < 2; ++j) {   // Vt tile: 64 c-rows x 128 B (stride 4 KB)
            int row = j * 32 + srow;
            int g = sc ^ fsw(row);
            gl_lds16(Vt + ((size_t)(b * D_MODEL) + h * DKH + row) * SEQ + kbase + g * 8,
                     &lV[(j * 32 + wv * 8) * 64]);
        }
#pragma unroll
        for (int j = 0; j < 4; ++j) {   // rz tile: 128 q-rows x 128 B (stride 4 KB)
            int row = j * 32 + srow;
            int g = sc ^ fsw(row);
            gl_lds16(rz + ((size_t)(b * SEQ) + q0 + row) * SEQ + kbase + g * 8,
                     &lrz[(j * 32 + wv * 8) * 64]);
        }
        __syncthreads();

#pragma unroll
        for (int gr = 0; gr < 2; ++gr) {  // two 32-key groups
            f32x4 sf[2][2] = {};
#pragma unroll
            for (int sel = 0; sel < 2; ++sel) {
                int key = gr * 32 + perm + sel * 4;
#pragma unroll
                for (int ks = 0; ks < 2; ++ks) {
                    uint4 kfv = *(const uint4*)&lK[key * 64 +
                                                   ((ks * 4 + quad) ^ fsw(key)) * 8];
                    sf[sel][0] = mfma16(kfv, qf[0][ks], sf[sel][0]);
                    sf[sel][1] = mfma16(kfv, qf[1][ks], sf[sel][1]);
                }
            }
            uint4 pk[2];
#pragma unroll
            for (int qs = 0; qs < 2; ++qs) {
                int qrow = wv * 32 + qs * 16 + lm;
                uint4 rq = *(const uint4*)&lrz[qrow * 64 +
                                               ((gr * 4 + quad) ^ fsw(qrow)) * 8];
                float p00 = __expf(sf[0][qs][0] * SCALE) * bflo(rq.x);
                float p01 = __expf(sf[0][qs][1] * SCALE) * bfhi(rq.x);
                float p02 = __expf(sf[0][qs][2] * SCALE) * bflo(rq.y);
                float p03 = __expf(sf[0][qs][3] * SCALE) * bfhi(rq.y);
                float p10 = __expf(sf[1][qs][0] * SCALE) * bflo(rq.z);
                float p11 = __expf(sf[1][qs][1] * SCALE) * bfhi(rq.z);
                float p12 = __expf(sf[1][qs][2] * SCALE) * bflo(rq.w);
                float p13 = __expf(sf[1][qs][3] * SCALE) * bfhi(rq.w);
                pk[qs].x = pack2rn(p00, p01);
                pk[qs].y = pack2rn(p02, p03);
                pk[qs].z = pack2rn(p10, p11);
                pk[qs].w = pack2rn(p12, p13);
            }
#pragma unroll
            for (int ct = 0; ct < 4; ++ct) {
                int vrow = ct * 16 + lm;
                uint4 vfv = *(const uint4*)&lV[vrow * 64 +
                                               ((gr * 4 + quad) ^ fsw(vrow)) * 8];
                oa[ct][0] = mfma16(vfv, pk[0], oa[ct][0]);
                oa[ct][1] = mfma16(vfv, pk[1], oa[ct][1]);
            }
        }
    }

    unsigned short* op = OP + (size_t)ksl * NTOK * D_MODEL;
#pragma unroll
    for (int ct = 0; ct < 4; ++ct)
#pragma unroll
        for (int qs = 0; qs < 2; ++qs) {
            uint2 st = { pack2rn(oa[ct][qs][0], oa[ct][qs][1]),
                         pack2rn(oa[ct][qs][2], oa[ct][qs][3]) };
            *(uint2*)(op + (hb + q0w + qs * 16 + lm) * DKH + ct * 16 + quad * 4) = st;
        }
}

extern "C" void kernel_launch(void* const* d_in, const int* in_sizes, int n_in,
                              void* d_out, int out_size, void* d_ws, size_t ws_size,
                              hipStream_t stream)
{
    const float* x  = (const float*)d_in[0];
    const float* Wq = (const float*)d_in[1];
    const float* bq = (const float*)d_in[2];
    const float* Wk = (const float*)d_in[3];
    const float* bk = (const float*)d_in[4];
    const float* Wv = (const float*)d_in[5];
    const float* bv = (const float*)d_in[6];
    const float* Wo = (const float*)d_in[7];
    const float* bo = (const float*)d_in[8];
    float* out = (float*)d_out;

    const size_t M  = (size_t)NTOK * D_MODEL;      // 4,194,304
    const size_t RZ = (size_t)NB * SEQ * SEQ;      // 8,388,608
    const size_t WE = (size_t)D_MODEL * D_MODEL;
    unsigned short* ws = (unsigned short*)d_ws;
    unsigned short* rzb = ws;            // aliases xb (xb dead after projs)
    unsigned short* xb  = ws;
    unsigned short* Qh  = ws + RZ;       // per-head [(b,h,q)][dk]
    unsigned short* Kh  = Qh + M;
    unsigned short* Vt  = Kh + M;        // [b][c][s]
    unsigned short* OP  = Vt + M;        // KS per-head partials; early alias: Wb
    unsigned short* WbQ = OP;
    unsigned short* WbK = OP + WE;
    unsigned short* WbV = OP + 2 * WE;

    const size_t need2 = (RZ + 3 * M + 2 * M) * sizeof(unsigned short);  // 58.7 MB
    const int KS = (ws_size >= need2) ? 2 : 1;

    cvt_k<<<2048, 256, 0, stream>>>(x, xb);
    cvt_k<<<512, 256, 0, stream>>>(Wq, WbQ);
    cvt_k<<<512, 256, 0, stream>>>(Wk, WbK);
    cvt_k<<<512, 256, 0, stream>>>(Wv, WbV);
    dim3 gg(16, 32);
    gemm_qkv<0><<<gg, 256, 0, stream>>>(xb, WbQ, bq, Qh);
    gemm_qkv<0><<<gg, 256, 0, stream>>>(xb, WbK, bk, Kh);
    gemm_qkv<1><<<gg, 256, 0, stream>>>(xb, WbV, bv, Vt);
    zker2<<<dim3(16, 16, NB), 256, 0, stream>>>(Qh, Kh, rzb);
    if (KS == 2) {
        attn3<2><<<dim3(16, NB * NH, 2), 256, 0, stream>>>(Qh, Kh, Vt, rzb, OP);
        gemm_osum<2><<<gg, 256, 0, stream>>>(OP, Wo, bo, out);
    } else {
        attn3<1><<<dim3(16, NB * NH, 1), 256, 0, stream>>>(Qh, Kh, Vt, rzb, OP);
        gemm_osum<1><<<gg, 256, 0, stream>>>(OP, Wo, bo, out);
    }
}